// Round 1
// baseline (391.669 us; speedup 1.0000x reference)
//
#include <hip/hip_runtime.h>

typedef short bf16x8 __attribute__((ext_vector_type(8)));
typedef float f32x4 __attribute__((ext_vector_type(4)));
typedef unsigned int u32;
typedef unsigned short u16;

__device__ __forceinline__ u16 f2bf(float x) {
  union { float f; u32 u; } v; v.f = x;
  u32 r = (v.u + 0x7fffu + ((v.u >> 16) & 1u)) >> 16;
  return (u16)r;
}
__device__ __forceinline__ u32 pk2(float a, float b) {
  return (u32)f2bf(a) | ((u32)f2bf(b) << 16);
}

// ---------- kernel 1: features f32 -> bf16 table in ws ----------
__global__ void feat_cvt(const float* __restrict__ src, u16* __restrict__ dst, int n4) {
  int i = blockIdx.x * 256 + threadIdx.x;
  if (i < n4) {
    float4 v = ((const float4*)src)[i];
    ushort4 o;
    o.x = f2bf(v.x); o.y = f2bf(v.y); o.z = f2bf(v.z); o.w = f2bf(v.w);
    ((ushort4*)dst)[i] = o;
  }
}

// ---------- kernel 2: k_values -> bf16 B-fragment table ----------
// contraction index idx(kp,f) = 512*(f>>5) + 128*(kp>>2) + 8*(f&15) + 4*((f>>4)&1) + (kp&3)
// kvb slot t = (sb*4+ct2)*64 + lane holds 8 bf16: B[idx = sb*32 + 8*(lane>>4)+j][c = ct2*16 + (lane&15)]
__global__ void kv_stage(const float* __restrict__ kv, u16* __restrict__ kvb) {
  int t = blockIdx.x * 256 + threadIdx.x;   // 8192 slots
  int l = t & 63;
  int tile = t >> 6;                        // 0..127
  int ct2 = tile & 3, sb = tile >> 2;
  int c = ct2 * 16 + (l & 15);
  u32 q[4];
#pragma unroll
  for (int jp = 0; jp < 4; ++jp) {
    u16 vv[2];
#pragma unroll
    for (int h = 0; h < 2; ++h) {
      int j = jp * 2 + h;
      int idx = sb * 32 + 8 * (l >> 4) + j;
      int reg  = idx & 3;
      int ctlo = (idx >> 2) & 1;
      int fl   = (idx >> 3) & 15;
      int kh   = (idx >> 7) & 3;
      int cthi = (idx >> 9) & 1;
      int kp = kh * 4 + reg;
      int f  = (cthi * 2 + ctlo) * 16 + fl;
      float val = (kp < 15) ? kv[(kp * 64 + f) * 64 + c] : 0.f;
      vv[h] = f2bf(val);
    }
    q[jp] = (u32)vv[0] | ((u32)vv[1] << 16);
  }
  ((uint4*)kvb)[t] = make_uint4(q[0], q[1], q[2], q[3]);
}

// ---------- main fused kernel: 1 wave per 16 output points ----------
__global__ __launch_bounds__(64, 1) void kpconv_main(
    const float* __restrict__ points,
    const float* __restrict__ outpts,
    const int*   __restrict__ nbr,
    const u16*   __restrict__ featg,   // [N][64] bf16
    const u16*   __restrict__ kvb,     // [128 tiles][64 lanes][8] bf16
    const float* __restrict__ kpts,    // [15][3]
    float* __restrict__ out, int M)
{
  __shared__ __align__(16) u16 featB[2048];      // 4KB: ushort idx = ct*512 + lane*8 + j
  __shared__ __align__(16) u16 wfs[16 * 1024];   // 32KB wf rows, swizzled
  __shared__ float npx[32], npy[32], npz[32];
  __shared__ int nidx[32];

  const int l = threadIdx.x;
  const int khi = l >> 4, flo = l & 15;
  const int mbase = blockIdx.x * 16;

  float kx = 0.f, ky = 0.f, kz = 0.f;
  if (flo < 15) { kx = kpts[flo*3+0]; ky = kpts[flo*3+1]; kz = kpts[flo*3+2]; }

  f32x4 acc0 = {0.f,0.f,0.f,0.f}, acc1 = acc0, acc2 = acc0, acc3 = acc0;
  const f32x4 zero = {0.f,0.f,0.f,0.f};

  for (int mi = 0; mi < 16; ++mi) {
    int m0 = mbase + mi;
    bool mvalid = m0 < M;
    int m = mvalid ? m0 : (M - 1);
    __syncthreads();                       // WAR protection vs previous iter reads
    if (l < 32) {
      int id = nbr[m * 32 + l];
      nidx[l] = id;
      npx[l] = points[id*3+0]; npy[l] = points[id*3+1]; npz[l] = points[id*3+2];
    }
    float ox = outpts[m*3+0], oy = outpts[m*3+1], oz = outpts[m*3+2];
    __syncthreads();

    // gather neighbor features (lane = feature column), pack 8 per n-block -> b128 LDS write
#pragma unroll
    for (int a = 0; a < 4; ++a) {
      u32 p[4];
#pragma unroll
      for (int jp = 0; jp < 4; ++jp) {
        u16 v0 = featg[(u32)nidx[8*a + 2*jp + 0] * 64u + (u32)l];
        u16 v1 = featg[(u32)nidx[8*a + 2*jp + 1] * 64u + (u32)l];
        p[jp] = (u32)v0 | ((u32)v1 << 16);
      }
      *(uint4*)&featB[khi*512 + a*128 + flo*8] = make_uint4(p[0], p[1], p[2], p[3]);
    }
    __syncthreads();

    // A-fragment: w[kp = flo][n = 8*khi + j]
    bf16x8 aw;
#pragma unroll
    for (int j = 0; j < 8; ++j) {
      int n = 8*khi + j;
      float dx = npx[n] - ox - kx;
      float dy = npy[n] - oy - ky;
      float dz = npz[n] - oz - kz;
      float w = 1.f - sqrtf(dx*dx + dy*dy + dz*dz);
      w = (flo < 15 && mvalid) ? fmaxf(w, 0.f) : 0.f;
      aw[j] = (short)f2bf(w);
    }

    // step-1 MFMAs: wf[kp][f] for this m
    f32x4 wf0 = __builtin_amdgcn_mfma_f32_16x16x32_bf16(aw, *(bf16x8*)&featB[0*512 + l*8], zero, 0,0,0);
    f32x4 wf1 = __builtin_amdgcn_mfma_f32_16x16x32_bf16(aw, *(bf16x8*)&featB[1*512 + l*8], zero, 0,0,0);
    f32x4 wf2 = __builtin_amdgcn_mfma_f32_16x16x32_bf16(aw, *(bf16x8*)&featB[2*512 + l*8], zero, 0,0,0);
    f32x4 wf3 = __builtin_amdgcn_mfma_f32_16x16x32_bf16(aw, *(bf16x8*)&featB[3*512 + l*8], zero, 0,0,0);

    // write wf row mi: 16 consecutive bf16 per lane = 2 x b128, XOR-swizzled
    uint4 s0 = make_uint4(pk2(wf0[0],wf0[1]), pk2(wf0[2],wf0[3]), pk2(wf1[0],wf1[1]), pk2(wf1[2],wf1[3]));
    uint4 s1 = make_uint4(pk2(wf2[0],wf2[1]), pk2(wf2[2],wf2[3]), pk2(wf3[0],wf3[1]), pk2(wf3[2],wf3[3]));
    u32 b0 = (u32)(mi*2048 + l*16) ^ ((u32)(mi & 7) << 4);
    *(uint4*)((char*)wfs + b0)          = s0;
    *(uint4*)((char*)wfs + (b0 + 1024)) = s1;
  }
  __syncthreads();

  // step-2: out[16 x 64] = WF[16 x 1024] @ KV[1024 x 64], 32 K-steps
  for (int sb = 0; sb < 32; ++sb) {
    u32 ra = (u32)(flo*2048 + sb*64 + khi*16) ^ ((u32)(flo & 7) << 4);
    bf16x8 af = *(bf16x8*)((char*)wfs + ra);
    const u16* kb = kvb + (u32)(sb*4*64 + l) * 8u;
    acc0 = __builtin_amdgcn_mfma_f32_16x16x32_bf16(af, *(const bf16x8*)(kb + 0*512),  acc0, 0,0,0);
    acc1 = __builtin_amdgcn_mfma_f32_16x16x32_bf16(af, *(const bf16x8*)(kb + 1*512),  acc1, 0,0,0);
    acc2 = __builtin_amdgcn_mfma_f32_16x16x32_bf16(af, *(const bf16x8*)(kb + 2*512),  acc2, 0,0,0);
    acc3 = __builtin_amdgcn_mfma_f32_16x16x32_bf16(af, *(const bf16x8*)(kb + 3*512),  acc3, 0,0,0);
  }

  // epilogue: row = 4*khi + r, col = ct2*16 + flo
#pragma unroll
  for (int r = 0; r < 4; ++r) {
    int m = mbase + 4*khi + r;
    if (m < M) {
      float* o = out + (u32)m * 64u;
      o[ 0 + flo] = acc0[r];
      o[16 + flo] = acc1[r];
      o[32 + flo] = acc2[r];
      o[48 + flo] = acc3[r];
    }
  }
}

extern "C" void kernel_launch(void* const* d_in, const int* in_sizes, int n_in,
                              void* d_out, int out_size, void* d_ws, size_t ws_size,
                              hipStream_t stream) {
  const float* points   = (const float*)d_in[0];
  const float* features = (const float*)d_in[1];
  const float* outpts   = (const float*)d_in[2];
  const int*   nbridx   = (const int*)d_in[3];
  const float* kpts     = (const float*)d_in[4];
  const float* kvals    = (const float*)d_in[5];
  float* out = (float*)d_out;

  int N = in_sizes[0] / 3;   // input points
  int M = in_sizes[2] / 3;   // output points

  u16* featg = (u16*)d_ws;                                  // N*64 bf16
  u16* kvb   = (u16*)((char*)d_ws + (size_t)N * 64 * 2);    // 128KB fragment table

  int n4 = (N * 64) / 4;
  feat_cvt<<<(n4 + 255) / 256, 256, 0, stream>>>(features, featg, n4);
  kv_stage<<<32, 256, 0, stream>>>(kvals, kvb);
  kpconv_main<<<(M + 15) / 16, 64, 0, stream>>>(points, outpts, nbridx, featg, kvb, kpts, out, M);
}

// Round 2
// 209.880 us; speedup vs baseline: 1.8662x; 1.8662x over previous
//
#include <hip/hip_runtime.h>

typedef short bf16x8 __attribute__((ext_vector_type(8)));
typedef float f32x4 __attribute__((ext_vector_type(4)));
typedef unsigned int u32;
typedef unsigned short u16;

__device__ __forceinline__ u16 f2bf(float x) {
  union { float f; u32 u; } v; v.f = x;
  u32 r = (v.u + 0x7fffu + ((v.u >> 16) & 1u)) >> 16;
  return (u16)r;
}
__device__ __forceinline__ u32 pk2(float a, float b) {
  return (u32)f2bf(a) | ((u32)f2bf(b) << 16);
}

// ---------- kernel 1: features f32 -> bf16 table in ws ----------
__global__ void feat_cvt(const float* __restrict__ src, u16* __restrict__ dst, int n4) {
  int i = blockIdx.x * 256 + threadIdx.x;
  if (i < n4) {
    float4 v = ((const float4*)src)[i];
    ushort4 o;
    o.x = f2bf(v.x); o.y = f2bf(v.y); o.z = f2bf(v.z); o.w = f2bf(v.w);
    ((ushort4*)dst)[i] = o;
  }
}

// ---------- kernel 2: k_values -> bf16 B-fragment table ----------
// contraction index idx(kp,f) = 512*(f>>5) + 128*(kp>>2) + 8*(f&15) + 4*((f>>4)&1) + (kp&3)
// kvb slot t = (sb*4+ct2)*64 + lane holds 8 bf16: B[idx = sb*32 + 8*(lane>>4)+j][c = ct2*16 + (lane&15)]
__global__ void kv_stage(const float* __restrict__ kv, u16* __restrict__ kvb) {
  int t = blockIdx.x * 256 + threadIdx.x;   // 8192 slots
  int l = t & 63;
  int tile = t >> 6;                        // 0..127
  int ct2 = tile & 3, sb = tile >> 2;
  int c = ct2 * 16 + (l & 15);
  u32 q[4];
#pragma unroll
  for (int jp = 0; jp < 4; ++jp) {
    u16 vv[2];
#pragma unroll
    for (int h = 0; h < 2; ++h) {
      int j = jp * 2 + h;
      int idx = sb * 32 + 8 * (l >> 4) + j;
      int reg  = idx & 3;
      int ctlo = (idx >> 2) & 1;
      int fl   = (idx >> 3) & 15;
      int kh   = (idx >> 7) & 3;
      int cthi = (idx >> 9) & 1;
      int kp = kh * 4 + reg;
      int f  = (cthi * 2 + ctlo) * 16 + fl;
      float val = (kp < 15) ? kv[(kp * 64 + f) * 64 + c] : 0.f;
      vv[h] = f2bf(val);
    }
    q[jp] = (u32)vv[0] | ((u32)vv[1] << 16);
  }
  ((uint4*)kvb)[t] = make_uint4(q[0], q[1], q[2], q[3]);
}

// ---------- main fused kernel: 4 waves per 16-m tile ----------
__global__ __launch_bounds__(256, 3) void kpconv_main(
    const float* __restrict__ points,
    const float* __restrict__ outpts,
    const int*   __restrict__ nbr,
    const u16*   __restrict__ featg,   // [N][64] bf16
    const u16*   __restrict__ kvb,     // [128 tiles][64 lanes][8] bf16
    const float* __restrict__ kpts,    // [15][3]
    float* __restrict__ out, int M)
{
  __shared__ __align__(16) u16 featB[4][2048];   // 16KB: per-wave B-fragment staging
  __shared__ __align__(16) u16 wfs[16 * 1024];   // 32KB wf rows, XOR-swizzled
  __shared__ float npx[4][32], npy[4][32], npz[4][32];
  __shared__ int nidx[4][32];

  const int tid = threadIdx.x;
  const int w = tid >> 6;          // wave id 0..3
  const int l = tid & 63;
  const int khi = l >> 4, flo = l & 15;
  const int mbase = blockIdx.x * 16;

  float kx = 0.f, ky = 0.f, kz = 0.f;
  if (flo < 15) { kx = kpts[flo*3+0]; ky = kpts[flo*3+1]; kz = kpts[flo*3+2]; }

  const f32x4 zero = {0.f,0.f,0.f,0.f};

  // ---- step 1: each wave computes wf rows for its 4 m's (no block barriers) ----
  for (int t = 0; t < 4; ++t) {
    int mi = w * 4 + t;
    int m0 = mbase + mi;
    bool mvalid = m0 < M;
    int m = mvalid ? m0 : (M - 1);

    if (l < 32) {
      int id = nbr[m * 32 + l];
      nidx[w][l] = id;
      npx[w][l] = points[id*3+0]; npy[w][l] = points[id*3+1]; npz[w][l] = points[id*3+2];
    }
    float ox = outpts[m*3+0], oy = outpts[m*3+1], oz = outpts[m*3+2];
    asm volatile("s_waitcnt lgkmcnt(0)" ::: "memory");   // nidx/np visible wave-wide
    __builtin_amdgcn_wave_barrier();

    // gather neighbor features (lane = feature column), pack 8 rows -> b128 LDS write
#pragma unroll
    for (int a = 0; a < 4; ++a) {
      u32 p[4];
#pragma unroll
      for (int jp = 0; jp < 4; ++jp) {
        u16 v0 = featg[(u32)nidx[w][8*a + 2*jp + 0] * 64u + (u32)l];
        u16 v1 = featg[(u32)nidx[w][8*a + 2*jp + 1] * 64u + (u32)l];
        p[jp] = (u32)v0 | ((u32)v1 << 16);
      }
      *(uint4*)&featB[w][khi*512 + a*128 + flo*8] = make_uint4(p[0], p[1], p[2], p[3]);
    }
    asm volatile("s_waitcnt lgkmcnt(0)" ::: "memory");   // featB writes done
    __builtin_amdgcn_wave_barrier();

    // A-fragment: w[kp = flo][n = 8*khi + j]
    bf16x8 aw;
#pragma unroll
    for (int j = 0; j < 8; ++j) {
      int n = 8*khi + j;
      float dx = npx[w][n] - ox - kx;
      float dy = npy[w][n] - oy - ky;
      float dz = npz[w][n] - oz - kz;
      float wt = 1.f - sqrtf(dx*dx + dy*dy + dz*dz);
      wt = (flo < 15 && mvalid) ? fmaxf(wt, 0.f) : 0.f;
      aw[j] = (short)f2bf(wt);
    }

    // step-1 MFMAs: wf[kp][f] for this m
    f32x4 wf0 = __builtin_amdgcn_mfma_f32_16x16x32_bf16(aw, *(bf16x8*)&featB[w][0*512 + l*8], zero, 0,0,0);
    f32x4 wf1 = __builtin_amdgcn_mfma_f32_16x16x32_bf16(aw, *(bf16x8*)&featB[w][1*512 + l*8], zero, 0,0,0);
    f32x4 wf2 = __builtin_amdgcn_mfma_f32_16x16x32_bf16(aw, *(bf16x8*)&featB[w][2*512 + l*8], zero, 0,0,0);
    f32x4 wf3 = __builtin_amdgcn_mfma_f32_16x16x32_bf16(aw, *(bf16x8*)&featB[w][3*512 + l*8], zero, 0,0,0);

    // write wf row mi: 16 consecutive bf16 per lane = 2 x b128, XOR-swizzled
    uint4 s0 = make_uint4(pk2(wf0[0],wf0[1]), pk2(wf0[2],wf0[3]), pk2(wf1[0],wf1[1]), pk2(wf1[2],wf1[3]));
    uint4 s1 = make_uint4(pk2(wf2[0],wf2[1]), pk2(wf2[2],wf2[3]), pk2(wf3[0],wf3[1]), pk2(wf3[2],wf3[3]));
    u32 b0 = (u32)(mi*2048 + l*16) ^ ((u32)(mi & 7) << 4);
    *(uint4*)((char*)wfs + b0)          = s0;
    *(uint4*)((char*)wfs + (b0 + 1024)) = s1;
  }
  __syncthreads();

  // ---- step 2: out[16 x 64] = WF[16 x 1024] @ KV[1024 x 64]; wave w owns column tile ct=w ----
  f32x4 acc = {0.f,0.f,0.f,0.f};
  for (int sb = 0; sb < 32; ++sb) {
    u32 ra = (u32)(flo*2048 + sb*64 + khi*16) ^ ((u32)(flo & 7) << 4);
    bf16x8 af = *(bf16x8*)((char*)wfs + ra);
    const u16* kb = kvb + (u32)((sb*4 + w)*64 + l) * 8u;
    acc = __builtin_amdgcn_mfma_f32_16x16x32_bf16(af, *(const bf16x8*)kb, acc, 0,0,0);
  }

  // epilogue: row = 4*khi + r, col = w*16 + flo
#pragma unroll
  for (int r = 0; r < 4; ++r) {
    int m = mbase + 4*khi + r;
    if (m < M) {
      out[(u32)m * 64u + (u32)(w*16 + flo)] = acc[r];
    }
  }
}

extern "C" void kernel_launch(void* const* d_in, const int* in_sizes, int n_in,
                              void* d_out, int out_size, void* d_ws, size_t ws_size,
                              hipStream_t stream) {
  const float* points   = (const float*)d_in[0];
  const float* features = (const float*)d_in[1];
  const float* outpts   = (const float*)d_in[2];
  const int*   nbridx   = (const int*)d_in[3];
  const float* kpts     = (const float*)d_in[4];
  const float* kvals    = (const float*)d_in[5];
  float* out = (float*)d_out;

  int N = in_sizes[0] / 3;   // input points
  int M = in_sizes[2] / 3;   // output points

  u16* featg = (u16*)d_ws;                                  // N*64 bf16
  u16* kvb   = (u16*)((char*)d_ws + (size_t)N * 64 * 2);    // 128KB fragment table

  int n4 = (N * 64) / 4;
  feat_cvt<<<(n4 + 255) / 256, 256, 0, stream>>>(features, featg, n4);
  kv_stage<<<32, 256, 0, stream>>>(kvals, kvb);
  kpconv_main<<<(M + 15) / 16, 256, 0, stream>>>(points, outpts, nbridx, featg, kvb, kpts, out, M);
}